// Round 1
// baseline (966.580 us; speedup 1.0000x reference)
//
#include <hip/hip_runtime.h>

// ---------------------------------------------------------------------------
// MultiModalRelationGraph: 5x input proj -> 3x GAT (structured graph) -> LN -> pool
// Graph structure is fixed & tiny-degree (<=5 incoming / node) => closed-form
// per-dst softmax, no atomics, no edge lists.
// Node layout: region i in [i*8192, (i+1)*8192), node = i*8192 + b*512 + t.
// Audio: 32768 + b*1024 + ta.
// ---------------------------------------------------------------------------

typedef unsigned short u16;
typedef unsigned int u32;
typedef __bf16 bf16x8 __attribute__((ext_vector_type(8)));
typedef float f32x4 __attribute__((ext_vector_type(4)));

__device__ __forceinline__ u16 f2bf(float f) {
  union { float f; u32 u; } v; v.f = f;
  u32 u = v.u + 0x7FFFu + ((v.u >> 16) & 1u);  // RNE
  return (u16)(u >> 16);
}
__device__ __forceinline__ float bf2f(u16 x) {
  union { u32 u; float f; } v; v.u = ((u32)x) << 16;
  return v.f;
}
__device__ __forceinline__ float4 load_bf4(const u16* p) {
  ushort4 s = *(const ushort4*)p;
  float4 r; r.x = bf2f(s.x); r.y = bf2f(s.y); r.z = bf2f(s.z); r.w = bf2f(s.w);
  return r;
}
__device__ __forceinline__ float lrelu(float v) { return v > 0.f ? v : 0.2f * v; }

// ---------------- fp32 -> bf16 elementwise convert (float4 granular) -------
__global__ __launch_bounds__(256) void cvt_kernel(const float* __restrict__ src,
                                                  u16* __restrict__ dst, int n4) {
  int i = blockIdx.x * 256 + threadIdx.x;
  if (i < n4) {
    float4 v = ((const float4*)src)[i];
    ushort4 o;
    o.x = f2bf(v.x); o.y = f2bf(v.y); o.z = f2bf(v.z); o.w = f2bf(v.w);
    ((ushort4*)dst)[i] = o;
  }
}

// ---------------- W [K][N] fp32 -> Wt [N][K] bf16 ---------------------------
__global__ void transpose_cvt_kernel(const float* __restrict__ W,
                                     u16* __restrict__ Wt, int K, int N) {
  __shared__ float tile[32][33];
  int k0 = blockIdx.x * 32, n0 = blockIdx.y * 32;
  int tx = threadIdx.x, ty = threadIdx.y;  // 32x8
#pragma unroll
  for (int i = 0; i < 32; i += 8)
    tile[ty + i][tx] = W[(size_t)(k0 + ty + i) * N + n0 + tx];
  __syncthreads();
#pragma unroll
  for (int i = 0; i < 32; i += 8)
    Wt[(size_t)(n0 + ty + i) * K + k0 + tx] = f2bf(tile[tx][ty + i]);
}

// ---------------- bf16 MFMA GEMM: C[M,Nout] = A[M,K] @ Bt[Nout,K]^T ---------
// 128x128 block tile, 4 waves each 64x64 (4x4 of 16x16x32 MFMA), BK=32.
// grid = (Nout/128, M/128): consecutive blocks share the A tile (L2 reuse).
// Output bf16, optional fp32 bias added per column.
__global__ __launch_bounds__(256) void gemm_kernel(
    const u16* __restrict__ A, const u16* __restrict__ Bt, u16* __restrict__ C,
    const float* __restrict__ bias, int K, int ldc) {
  __shared__ u16 As[128 * 40];  // row stride 40 (+8 pad keeps 16B align, kills conflicts)
  __shared__ u16 Bs[128 * 40];
  const int tid = threadIdx.x;
  const int wave = tid >> 6, lane = tid & 63;
  const int blockRow = blockIdx.y * 128, blockCol = blockIdx.x * 128;
  const int wr = (wave >> 1) * 64, wc = (wave & 1) * 64;
  const int lr = lane & 15, lq = lane >> 4;
  const int srow = wave * 16 + (lane >> 2);  // staging row 0..63
  const int skof = (lane & 3) * 8;           // staging k offset (elements)

  f32x4 acc[4][4] = {};

  for (int k0 = 0; k0 < K; k0 += 32) {
    __syncthreads();
    uint4 a0 = *(const uint4*)(A + (size_t)(blockRow + srow) * K + k0 + skof);
    uint4 a1 = *(const uint4*)(A + (size_t)(blockRow + 64 + srow) * K + k0 + skof);
    uint4 b0 = *(const uint4*)(Bt + (size_t)(blockCol + srow) * K + k0 + skof);
    uint4 b1 = *(const uint4*)(Bt + (size_t)(blockCol + 64 + srow) * K + k0 + skof);
    *(uint4*)(&As[srow * 40 + skof]) = a0;
    *(uint4*)(&As[(64 + srow) * 40 + skof]) = a1;
    *(uint4*)(&Bs[srow * 40 + skof]) = b0;
    *(uint4*)(&Bs[(64 + srow) * 40 + skof]) = b1;
    __syncthreads();
    bf16x8 af[4], bfr[4];
#pragma unroll
    for (int mi = 0; mi < 4; ++mi)
      af[mi] = *(const bf16x8*)(&As[(wr + mi * 16 + lr) * 40 + lq * 8]);
#pragma unroll
    for (int ni = 0; ni < 4; ++ni)
      bfr[ni] = *(const bf16x8*)(&Bs[(wc + ni * 16 + lr) * 40 + lq * 8]);
#pragma unroll
    for (int mi = 0; mi < 4; ++mi)
#pragma unroll
      for (int ni = 0; ni < 4; ++ni)
        acc[mi][ni] = __builtin_amdgcn_mfma_f32_16x16x32_bf16(af[mi], bfr[ni],
                                                              acc[mi][ni], 0, 0, 0);
  }
  // epilogue: C/D layout col=lane&15, row=(lane>>4)*4+reg  [measured m89/m91]
#pragma unroll
  for (int mi = 0; mi < 4; ++mi) {
#pragma unroll
    for (int ni = 0; ni < 4; ++ni) {
      const int col = blockCol + wc + ni * 16 + lr;
      const float bv = bias ? bias[col] : 0.0f;
#pragma unroll
      for (int r = 0; r < 4; ++r) {
        const int row = blockRow + wr + mi * 16 + lq * 4 + r;
        C[(size_t)row * ldc + col] = f2bf(acc[mi][ni][r] + bv);
      }
    }
  }
}

// ---------------- per-node attention scalars: as/ad[n,h] = sum_c h*a --------
__global__ __launch_bounds__(256) void alpha_kernel(
    const u16* __restrict__ h, const float* __restrict__ a_s,
    const float* __restrict__ a_d, float* __restrict__ asb, float* __restrict__ adb) {
  const int n = blockIdx.x;
  const int tid = threadIdx.x;
  const int head = tid >> 6, lane = tid & 63;
  const int c = head * 256 + lane * 4;
  float4 hv = load_bf4(h + (size_t)n * 1024 + c);
  float4 sv = *(const float4*)(a_s + c);
  float4 dv = *(const float4*)(a_d + c);
  float ss = hv.x * sv.x + hv.y * sv.y + hv.z * sv.z + hv.w * sv.w;
  float sd = hv.x * dv.x + hv.y * dv.y + hv.z * dv.z + hv.w * dv.w;
#pragma unroll
  for (int off = 32; off; off >>= 1) {
    ss += __shfl_down(ss, off);
    sd += __shfl_down(sd, off);
  }
  if (lane == 0) {
    asb[n * 4 + head] = ss;
    adb[n * 4 + head] = sd;
  }
}

// ---------------- region-dst aggregation (4 dsts per (b,t) block) -----------
// srcs of dst j at (b,t): regions 0..3 at (b,t) (cross + self), region j at t-1.
template <bool MEAN>
__global__ __launch_bounds__(256) void region_agg_kernel(
    const u16* __restrict__ h, const float* __restrict__ asb,
    const float* __restrict__ adb, const float* __restrict__ bias,
    void* __restrict__ out) {
  const int bt = blockIdx.x;  // b*512 + t
  const int t = bt & 511;
  const int tid = threadIdx.x;
  __shared__ float alpha[4][4][5];  // [dst j][head][src k]
  if (tid < 16) {
    const int j = tid >> 2, hh = tid & 3;
    const int nj = j * 8192 + bt;
    const float ad = adb[nj * 4 + hh];
    float e[5];
#pragma unroll
    for (int r = 0; r < 4; ++r) e[r] = lrelu(asb[(r * 8192 + bt) * 4 + hh] + ad);
    int cnt = 4;
    if (t > 0) { e[4] = lrelu(asb[(nj - 1) * 4 + hh] + ad); cnt = 5; }
    float m = e[0];
    for (int k = 1; k < cnt; ++k) m = fmaxf(m, e[k]);
    float s = 0.f, ex[5];
    for (int k = 0; k < cnt; ++k) { ex[k] = __expf(e[k] - m); s += ex[k]; }
    const float inv = 1.f / (s + 1e-16f);
#pragma unroll
    for (int k = 0; k < 5; ++k) alpha[j][hh][k] = (k < cnt) ? ex[k] * inv : 0.f;
  }
  __syncthreads();
  const int c4 = tid * 4;
  const int head = tid >> 6;
  float4 hv[4];
#pragma unroll
  for (int r = 0; r < 4; ++r) hv[r] = load_bf4(h + (size_t)(r * 8192 + bt) * 1024 + c4);

  if constexpr (!MEAN) {
    const float4 bv = *(const float4*)(bias + c4);
    u16* ob = (u16*)out;
#pragma unroll
    for (int j = 0; j < 4; ++j) {
      const float* al = &alpha[j][head][0];
      const float a0 = al[0], a1 = al[1], a2 = al[2], a3 = al[3], a4 = al[4];
      float4 acc;
      acc.x = a0 * hv[0].x + a1 * hv[1].x + a2 * hv[2].x + a3 * hv[3].x;
      acc.y = a0 * hv[0].y + a1 * hv[1].y + a2 * hv[2].y + a3 * hv[3].y;
      acc.z = a0 * hv[0].z + a1 * hv[1].z + a2 * hv[2].z + a3 * hv[3].z;
      acc.w = a0 * hv[0].w + a1 * hv[1].w + a2 * hv[2].w + a3 * hv[3].w;
      if (t > 0) {
        float4 hp = load_bf4(h + (size_t)(j * 8192 + bt - 1) * 1024 + c4);
        acc.x += a4 * hp.x; acc.y += a4 * hp.y; acc.z += a4 * hp.z; acc.w += a4 * hp.w;
      }
      ushort4 o;
      o.x = f2bf(acc.x + bv.x); o.y = f2bf(acc.y + bv.y);
      o.z = f2bf(acc.z + bv.z); o.w = f2bf(acc.w + bv.w);
      *(ushort4*)(ob + (size_t)(j * 8192 + bt) * 1024 + c4) = o;
    }
  } else {
    __shared__ float red[4][1024];
#pragma unroll
    for (int j = 0; j < 4; ++j) {
      const float* al = &alpha[j][head][0];
      const float a0 = al[0], a1 = al[1], a2 = al[2], a3 = al[3], a4 = al[4];
      float4 acc;
      acc.x = a0 * hv[0].x + a1 * hv[1].x + a2 * hv[2].x + a3 * hv[3].x;
      acc.y = a0 * hv[0].y + a1 * hv[1].y + a2 * hv[2].y + a3 * hv[3].y;
      acc.z = a0 * hv[0].z + a1 * hv[1].z + a2 * hv[2].z + a3 * hv[3].z;
      acc.w = a0 * hv[0].w + a1 * hv[1].w + a2 * hv[2].w + a3 * hv[3].w;
      if (t > 0) {
        float4 hp = load_bf4(h + (size_t)(j * 8192 + bt - 1) * 1024 + c4);
        acc.x += a4 * hp.x; acc.y += a4 * hp.y; acc.z += a4 * hp.z; acc.w += a4 * hp.w;
      }
      *(float4*)(&red[j][c4]) = acc;
    }
    __syncthreads();
    const float bb = bias[tid];
    float* of = (float*)out;
#pragma unroll
    for (int j = 0; j < 4; ++j) {
      float v = 0.25f * (red[j][tid] + red[j][tid + 256] + red[j][tid + 512] +
                         red[j][tid + 768]) + bb;
      of[(size_t)(j * 8192 + bt) * 256 + tid] = v;
    }
  }
}

// ---------------- audio-dst aggregation (1 node per block) ------------------
// even ta: srcs {self, left_eye(b,ta/2), right_eye(b,ta/2)}; odd ta: self only.
template <bool MEAN>
__global__ __launch_bounds__(256) void audio_agg_kernel(
    const u16* __restrict__ h, const float* __restrict__ asb,
    const float* __restrict__ adb, const float* __restrict__ bias,
    void* __restrict__ out) {
  const int idx = blockIdx.x;  // b*1024 + ta
  const int ta = idx & 1023;
  const int node = 32768 + idx;
  const int tid = threadIdx.x;
  const bool even = ((ta & 1) == 0);
  __shared__ float alpha[4][3];
  int le = 0, re = 0;
  if (even) {
    const int b = idx >> 10;
    const int t = ta >> 1;
    le = 8192 + b * 512 + t;
    re = 16384 + b * 512 + t;
    if (tid < 4) {
      const int hh = tid;
      const float ad = adb[node * 4 + hh];
      float e0 = lrelu(asb[node * 4 + hh] + ad);
      float e1 = lrelu(asb[le * 4 + hh] + ad);
      float e2 = lrelu(asb[re * 4 + hh] + ad);
      float m = fmaxf(e0, fmaxf(e1, e2));
      float x0 = __expf(e0 - m), x1 = __expf(e1 - m), x2 = __expf(e2 - m);
      float inv = 1.f / (x0 + x1 + x2 + 1e-16f);
      alpha[hh][0] = x0 * inv; alpha[hh][1] = x1 * inv; alpha[hh][2] = x2 * inv;
    }
    __syncthreads();
  }
  const int c4 = tid * 4;
  const int head = tid >> 6;
  float4 v = load_bf4(h + (size_t)node * 1024 + c4);
  if (even) {
    float4 v1 = load_bf4(h + (size_t)le * 1024 + c4);
    float4 v2 = load_bf4(h + (size_t)re * 1024 + c4);
    const float a0 = alpha[head][0], a1 = alpha[head][1], a2 = alpha[head][2];
    v.x = a0 * v.x + a1 * v1.x + a2 * v2.x;
    v.y = a0 * v.y + a1 * v1.y + a2 * v2.y;
    v.z = a0 * v.z + a1 * v1.z + a2 * v2.z;
    v.w = a0 * v.w + a1 * v1.w + a2 * v2.w;
  }
  if constexpr (!MEAN) {
    const float4 bv = *(const float4*)(bias + c4);
    ushort4 o;
    o.x = f2bf(v.x + bv.x); o.y = f2bf(v.y + bv.y);
    o.z = f2bf(v.z + bv.z); o.w = f2bf(v.w + bv.w);
    *(ushort4*)((u16*)out + (size_t)node * 1024 + c4) = o;
  } else {
    __shared__ float red[1024];
    *(float4*)(&red[c4]) = v;
    __syncthreads();
    float* of = (float*)out;
    of[(size_t)node * 256 + tid] =
        0.25f * (red[tid] + red[tid + 256] + red[tid + 512] + red[tid + 768]) + bias[tid];
  }
}

// ---------------- LayerNorm(256) + partial chunk pooling --------------------
// grid 768 = 16 chunks x 48 sub-blocks of 64 nodes; writes per-block partial sums.
__global__ __launch_bounds__(256) void ln_pool_kernel(
    const float* __restrict__ xf, const float* __restrict__ g,
    const float* __restrict__ bb, float* __restrict__ part) {
  const int chunk = blockIdx.x / 48;
  const int sub = blockIdx.x % 48;
  const int n0 = chunk * 3072 + sub * 64;
  const int c = threadIdx.x;
  const int wave = c >> 6, lane = c & 63;
  __shared__ float ls[8];
  const float gc = g[c], bc = bb[c];
  float accum = 0.f;
  for (int i = 0; i < 64; ++i) {
    const float v = xf[(size_t)(n0 + i) * 256 + c];
    float s = v, q = v * v;
#pragma unroll
    for (int off = 32; off; off >>= 1) {
      s += __shfl_down(s, off);
      q += __shfl_down(q, off);
    }
    if (lane == 0) { ls[wave] = s; ls[4 + wave] = q; }
    __syncthreads();
    const float st = ls[0] + ls[1] + ls[2] + ls[3];
    const float qt = ls[4] + ls[5] + ls[6] + ls[7];
    __syncthreads();
    const float mean = st * (1.f / 256.f);
    const float var = qt * (1.f / 256.f) - mean * mean;
    accum += (v - mean) * rsqrtf(var + 1e-5f) * gc + bc;
  }
  part[(size_t)blockIdx.x * 256 + c] = accum;
}

__global__ __launch_bounds__(256) void pool2_kernel(const float* __restrict__ part,
                                                    float* __restrict__ out) {
  const int chunk = blockIdx.x;
  const int c = threadIdx.x;
  float s = 0.f;
  for (int i = 0; i < 48; ++i) s += part[(size_t)(chunk * 48 + i) * 256 + c];
  out[chunk * 256 + c] = s * (1.f / 3072.f);
}

// ---------------------------------------------------------------------------
extern "C" void kernel_launch(void* const* d_in, const int* in_sizes, int n_in,
                              void* d_out, int out_size, void* d_ws, size_t ws_size,
                              hipStream_t stream) {
  const float* x_reg[4] = {(const float*)d_in[0], (const float*)d_in[1],
                           (const float*)d_in[2], (const float*)d_in[3]};
  const float* audio = (const float*)d_in[4];
  const float* w_reg[4] = {(const float*)d_in[5], (const float*)d_in[7],
                           (const float*)d_in[9], (const float*)d_in[11]};
  const float* b_reg[4] = {(const float*)d_in[6], (const float*)d_in[8],
                           (const float*)d_in[10], (const float*)d_in[12]};
  const float* w_aud = (const float*)d_in[13];
  const float* b_aud = (const float*)d_in[14];
  const float* Wl[3] = {(const float*)d_in[15], (const float*)d_in[19],
                        (const float*)d_in[23]};
  const float* as_in[3] = {(const float*)d_in[16], (const float*)d_in[20],
                           (const float*)d_in[24]};
  const float* ad_in[3] = {(const float*)d_in[17], (const float*)d_in[21],
                           (const float*)d_in[25]};
  const float* bias_l[3] = {(const float*)d_in[18], (const float*)d_in[22],
                            (const float*)d_in[26]};
  const float* ln_g = (const float*)d_in[27];
  const float* ln_b = (const float*)d_in[28];

  // workspace layout (200 MiB total)
  char* ws = (char*)d_ws;
  u16* h_bf = (u16*)ws;                       // [N,1024] bf16; aliased input-bf16 staging
  u16* in_bf = h_bf;                          // [N,512] bf16 (dead before L0 GEMM writes h)
  u16* xb = (u16*)(ws + 100663296);           // [N,1024] bf16 x buffer (in-place ping)
  float* xf = (float*)xb;                     // layer-2 output [N,256] fp32 (same buffer)
  float* asb = (float*)(ws + 201326592);      // [N,4]
  float* adb = (float*)(ws + 202113024);      // [N,4]
  u16* wt = (u16*)(ws + 202899456);           // transposed bf16 weights
  float* part = (float*)(ws + 208928768);     // 768*256 pooling partials

  u16* wtp[5];
  for (int r = 0; r < 5; ++r) wtp[r] = wt + (size_t)r * 131072;  // [256][512]
  u16* wt0 = wt + 655360;   // [1024][256]
  u16* wt1 = wt + 917504;   // [1024][1024]
  u16* wt2 = wt + 1966080;  // [1024][1024]

  // 1) inputs -> bf16 (contiguous [N,512], node-ordered)
  cvt_kernel<<<4096, 256, 0, stream>>>(x_reg[0], in_bf, 1048576);
  cvt_kernel<<<4096, 256, 0, stream>>>(x_reg[1], in_bf + 4194304, 1048576);
  cvt_kernel<<<4096, 256, 0, stream>>>(x_reg[2], in_bf + 8388608, 1048576);
  cvt_kernel<<<4096, 256, 0, stream>>>(x_reg[3], in_bf + 12582912, 1048576);
  cvt_kernel<<<8192, 256, 0, stream>>>(audio, in_bf + 16777216, 2097152);

  // 2) weights -> transposed bf16
  dim3 tb(32, 8);
  for (int r = 0; r < 4; ++r)
    transpose_cvt_kernel<<<dim3(16, 8), tb, 0, stream>>>(w_reg[r], wtp[r], 512, 256);
  transpose_cvt_kernel<<<dim3(16, 8), tb, 0, stream>>>(w_aud, wtp[4], 512, 256);
  transpose_cvt_kernel<<<dim3(8, 32), tb, 0, stream>>>(Wl[0], wt0, 256, 1024);
  transpose_cvt_kernel<<<dim3(32, 32), tb, 0, stream>>>(Wl[1], wt1, 1024, 1024);
  transpose_cvt_kernel<<<dim3(32, 32), tb, 0, stream>>>(Wl[2], wt2, 1024, 1024);

  // 3) input projections -> x0 bf16 [N,256]
  for (int r = 0; r < 4; ++r)
    gemm_kernel<<<dim3(2, 64), 256, 0, stream>>>(in_bf + (size_t)r * 4194304, wtp[r],
                                                 xb + (size_t)r * 2097152, b_reg[r],
                                                 512, 256);
  gemm_kernel<<<dim3(2, 128), 256, 0, stream>>>(in_bf + 16777216, wtp[4],
                                                xb + 8388608, b_aud, 512, 256);

  // 4) three GAT layers
  const u16* wl[3] = {wt0, wt1, wt2};
  const int Kl[3] = {256, 1024, 1024};
  for (int l = 0; l < 3; ++l) {
    gemm_kernel<<<dim3(8, 384), 256, 0, stream>>>(xb, wl[l], h_bf, nullptr, Kl[l], 1024);
    alpha_kernel<<<49152, 256, 0, stream>>>(h_bf, as_in[l], ad_in[l], asb, adb);
    if (l < 2) {
      region_agg_kernel<false><<<8192, 256, 0, stream>>>(h_bf, asb, adb, bias_l[l], xb);
      audio_agg_kernel<false><<<16384, 256, 0, stream>>>(h_bf, asb, adb, bias_l[l], xb);
    } else {
      region_agg_kernel<true><<<8192, 256, 0, stream>>>(h_bf, asb, adb, bias_l[l], xf);
      audio_agg_kernel<true><<<16384, 256, 0, stream>>>(h_bf, asb, adb, bias_l[l], xf);
    }
  }

  // 5) LayerNorm + chunk pooling -> out [16,256]
  ln_pool_kernel<<<768, 256, 0, stream>>>(xf, ln_g, ln_b, part);
  pool2_kernel<<<16, 256, 0, stream>>>(part, (float*)d_out);
}

// Round 2
// 846.007 us; speedup vs baseline: 1.1425x; 1.1425x over previous
//
#include <hip/hip_runtime.h>

// ---------------------------------------------------------------------------
// MultiModalRelationGraph: 5x input proj -> 3x GAT (structured graph) -> LN -> pool
// Graph is fixed & tiny-degree (<=5 in-edges/node) => closed-form per-dst
// softmax, no atomics, no edge lists.
// Node layout: region i in [i*8192,(i+1)*8192), node = i*8192 + b*512 + t.
// Audio: 32768 + b*1024 + ta.
// R2: GEMM uses global_load_lds(16B) + XOR-swizzled LDS (conflict-free b128
// reads) + XCD-aware block swizzle (A-tile L2 reuse); fused input proj + cvt.
// ---------------------------------------------------------------------------

typedef unsigned short u16;
typedef unsigned int u32;
typedef __bf16 bf16x8 __attribute__((ext_vector_type(8)));
typedef float f32x4 __attribute__((ext_vector_type(4)));

#define ASYNC16(gp, lp)                                                        \
  __builtin_amdgcn_global_load_lds(                                            \
      (const __attribute__((address_space(1))) void*)(gp),                     \
      (__attribute__((address_space(3))) void*)(lp), 16, 0, 0)

__device__ __forceinline__ u16 f2bf(float f) {
  union { float f; u32 u; } v; v.f = f;
  u32 u = v.u + 0x7FFFu + ((v.u >> 16) & 1u);  // RNE
  return (u16)(u >> 16);
}
__device__ __forceinline__ float bf2f(u16 x) {
  union { u32 u; float f; } v; v.u = ((u32)x) << 16;
  return v.f;
}
__device__ __forceinline__ float4 load_bf4(const u16* p) {
  ushort4 s = *(const ushort4*)p;
  float4 r; r.x = bf2f(s.x); r.y = bf2f(s.y); r.z = bf2f(s.z); r.w = bf2f(s.w);
  return r;
}
__device__ __forceinline__ float lrelu(float v) { return v > 0.f ? v : 0.2f * v; }

// ---------------- fp32 -> bf16 convert, all 5 inputs in one dispatch --------
struct CvtArgs { const float* p[5]; };
__global__ __launch_bounds__(256) void cvt_all_kernel(CvtArgs a,
                                                      u16* __restrict__ dst) {
  int i = blockIdx.x * 256 + threadIdx.x;  // float4 granule over 25165824 floats
  if (i >= 6291456) return;
  const float* src;
  int off;
  if (i < 4194304) { src = a.p[i >> 20]; off = i & 1048575; }
  else             { src = a.p[4];       off = i - 4194304; }
  float4 v = ((const float4*)src)[off];
  ushort4 o;
  o.x = f2bf(v.x); o.y = f2bf(v.y); o.z = f2bf(v.z); o.w = f2bf(v.w);
  ((ushort4*)dst)[i] = o;
}

// ---------------- W [K][N] fp32 -> Wt [N][K] bf16 ---------------------------
__global__ void transpose_cvt_kernel(const float* __restrict__ W,
                                     u16* __restrict__ Wt, int K, int N) {
  __shared__ float tile[32][33];
  int k0 = blockIdx.x * 32, n0 = blockIdx.y * 32;
  int tx = threadIdx.x, ty = threadIdx.y;  // 32x8
#pragma unroll
  for (int i = 0; i < 32; i += 8)
    tile[ty + i][tx] = W[(size_t)(k0 + ty + i) * N + n0 + tx];
  __syncthreads();
#pragma unroll
  for (int i = 0; i < 32; i += 8)
    Wt[(size_t)(n0 + ty + i) * K + k0 + tx] = f2bf(tile[tx][ty + i]);
}

// ---------------- shared MFMA GEMM body -------------------------------------
// C[M,Nout] = A[M,K] @ Bt[Nout,K]^T; 128x128 tile, 4 waves x (4x4 16x16x32).
// LDS [128][32] unpadded; global_load_lds 16B; XOR granule swizzle
// c' = c ^ ((row>>1)&3) so each quarter-wave b128 read phase is 2-way (free).
__device__ __forceinline__ void gemm_body(
    const u16* __restrict__ A, const u16* __restrict__ Bt, u16* __restrict__ C,
    const float* __restrict__ bias, int K, int ldc, int blockRow, int blockCol,
    u16* As, u16* Bs) {
  const int tid = threadIdx.x;
  const int wave = tid >> 6, lane = tid & 63;
  const int wr = (wave >> 1) * 64, wc = (wave & 1) * 64;
  const int lr = lane & 15, lq = lane >> 4;

  // staging: lane covers LDS granule (wave*16 + lane/4, lane%4); its global
  // source granule col = (lane%4) ^ ((row>>1)&3)   (row%64 invariant)
  const int sRow = wave * 16 + (lane >> 2);
  const int sGc = (lane & 3) ^ ((sRow >> 1) & 3);
  const size_t aOff0 = (size_t)(blockRow + sRow) * K + sGc * 8;
  const size_t aOff1 = aOff0 + (size_t)64 * K;
  const size_t bOff0 = (size_t)(blockCol + sRow) * K + sGc * 8;
  const size_t bOff1 = bOff0 + (size_t)64 * K;
  u16* asb0 = As + wave * 512;          // wave-uniform LDS bases
  u16* asb1 = As + wave * 512 + 2048;
  u16* bsb0 = Bs + wave * 512;
  u16* bsb1 = Bs + wave * 512 + 2048;

  f32x4 acc[4][4] = {};

  for (int k0 = 0; k0 < K; k0 += 32) {
    __syncthreads();
    ASYNC16(A + aOff0 + k0, asb0);
    ASYNC16(A + aOff1 + k0, asb1);
    ASYNC16(Bt + bOff0 + k0, bsb0);
    ASYNC16(Bt + bOff1 + k0, bsb1);
    __syncthreads();
    bf16x8 af[4], bfr[4];
#pragma unroll
    for (int mi = 0; mi < 4; ++mi) {
      const int R = wr + mi * 16 + lr;
      const int cp = lq ^ ((R >> 1) & 3);
      af[mi] = *(const bf16x8*)(&As[R * 32 + cp * 8]);
    }
#pragma unroll
    for (int ni = 0; ni < 4; ++ni) {
      const int R = wc + ni * 16 + lr;
      const int cp = lq ^ ((R >> 1) & 3);
      bfr[ni] = *(const bf16x8*)(&Bs[R * 32 + cp * 8]);
    }
#pragma unroll
    for (int mi = 0; mi < 4; ++mi)
#pragma unroll
      for (int ni = 0; ni < 4; ++ni)
        acc[mi][ni] = __builtin_amdgcn_mfma_f32_16x16x32_bf16(af[mi], bfr[ni],
                                                              acc[mi][ni], 0, 0, 0);
  }
  // epilogue: C/D layout col=lane&15, row=(lane>>4)*4+reg  [measured m89/m91]
#pragma unroll
  for (int mi = 0; mi < 4; ++mi) {
#pragma unroll
    for (int ni = 0; ni < 4; ++ni) {
      const int col = blockCol + wc + ni * 16 + lr;
      const float bv = bias ? bias[col] : 0.0f;
#pragma unroll
      for (int r = 0; r < 4; ++r) {
        const int row = blockRow + wr + mi * 16 + lq * 4 + r;
        C[(size_t)row * ldc + col] = f2bf(acc[mi][ni][r] + bv);
      }
    }
  }
}

// layer GEMM: gridDim.x==8 required; XCD swizzle (heuristic xcd = wgid%8):
// all 8 col-blocks of one A-row-strip land consecutively on one XCD.
__global__ __launch_bounds__(256) void gemm_kernel(
    const u16* __restrict__ A, const u16* __restrict__ Bt, u16* __restrict__ C,
    const float* __restrict__ bias, int K, int ldc) {
  __shared__ __align__(16) u16 As[128 * 32];
  __shared__ __align__(16) u16 Bs[128 * 32];
  const int w = blockIdx.y * 8 + blockIdx.x;
  const int k = w & 7, m = w >> 3;
  const int bx = m & 7, by = (m >> 3) * 8 + k;
  gemm_body(A, Bt, C, bias, K, ldc, by * 128, bx * 128, As, Bs);
}

// fused input projections: one dispatch, weight picked by row range.
struct ProjArgs { const u16* w[5]; const float* b[5]; };
__global__ __launch_bounds__(256) void proj_gemm_kernel(
    ProjArgs pa, const u16* __restrict__ A, u16* __restrict__ C) {
  __shared__ __align__(16) u16 As[128 * 32];
  __shared__ __align__(16) u16 Bs[128 * 32];
  const int blockRow = blockIdx.y * 128;
  const int reg = blockRow >= 32768 ? 4 : (blockRow >> 13);
  gemm_body(A, pa.w[reg], C, pa.b[reg], 512, 256, blockRow, blockIdx.x * 128,
            As, Bs);
}

// ---------------- per-node attention scalars: as/ad[n,h] = sum_c h*a --------
__global__ __launch_bounds__(256) void alpha_kernel(
    const u16* __restrict__ h, const float* __restrict__ a_s,
    const float* __restrict__ a_d, float* __restrict__ asb, float* __restrict__ adb) {
  const int n = blockIdx.x;
  const int tid = threadIdx.x;
  const int head = tid >> 6, lane = tid & 63;
  const int c = head * 256 + lane * 4;
  float4 hv = load_bf4(h + (size_t)n * 1024 + c);
  float4 sv = *(const float4*)(a_s + c);
  float4 dv = *(const float4*)(a_d + c);
  float ss = hv.x * sv.x + hv.y * sv.y + hv.z * sv.z + hv.w * sv.w;
  float sd = hv.x * dv.x + hv.y * dv.y + hv.z * dv.z + hv.w * dv.w;
#pragma unroll
  for (int off = 32; off; off >>= 1) {
    ss += __shfl_down(ss, off);
    sd += __shfl_down(sd, off);
  }
  if (lane == 0) {
    asb[n * 4 + head] = ss;
    adb[n * 4 + head] = sd;
  }
}

// ---------------- region-dst aggregation (4 dsts per (b,t) block) -----------
// srcs of dst j at (b,t): regions 0..3 at (b,t) (cross + self), region j at t-1.
template <bool MEAN>
__global__ __launch_bounds__(256) void region_agg_kernel(
    const u16* __restrict__ h, const float* __restrict__ asb,
    const float* __restrict__ adb, const float* __restrict__ bias,
    void* __restrict__ out) {
  const int bt = blockIdx.x;  // b*512 + t
  const int t = bt & 511;
  const int tid = threadIdx.x;
  __shared__ float alpha[4][4][5];  // [dst j][head][src k]
  if (tid < 16) {
    const int j = tid >> 2, hh = tid & 3;
    const int nj = j * 8192 + bt;
    const float ad = adb[nj * 4 + hh];
    float e[5];
#pragma unroll
    for (int r = 0; r < 4; ++r) e[r] = lrelu(asb[(r * 8192 + bt) * 4 + hh] + ad);
    int cnt = 4;
    if (t > 0) { e[4] = lrelu(asb[(nj - 1) * 4 + hh] + ad); cnt = 5; }
    float m = e[0];
    for (int k = 1; k < cnt; ++k) m = fmaxf(m, e[k]);
    float s = 0.f, ex[5];
    for (int k = 0; k < cnt; ++k) { ex[k] = __expf(e[k] - m); s += ex[k]; }
    const float inv = 1.f / (s + 1e-16f);
#pragma unroll
    for (int k = 0; k < 5; ++k) alpha[j][hh][k] = (k < cnt) ? ex[k] * inv : 0.f;
  }
  __syncthreads();
  const int c4 = tid * 4;
  const int head = tid >> 6;
  float4 hv[4];
#pragma unroll
  for (int r = 0; r < 4; ++r) hv[r] = load_bf4(h + (size_t)(r * 8192 + bt) * 1024 + c4);

  if constexpr (!MEAN) {
    const float4 bv = *(const float4*)(bias + c4);
    u16* ob = (u16*)out;
#pragma unroll
    for (int j = 0; j < 4; ++j) {
      const float* al = &alpha[j][head][0];
      const float a0 = al[0], a1 = al[1], a2 = al[2], a3 = al[3], a4 = al[4];
      float4 acc;
      acc.x = a0 * hv[0].x + a1 * hv[1].x + a2 * hv[2].x + a3 * hv[3].x;
      acc.y = a0 * hv[0].y + a1 * hv[1].y + a2 * hv[2].y + a3 * hv[3].y;
      acc.z = a0 * hv[0].z + a1 * hv[1].z + a2 * hv[2].z + a3 * hv[3].z;
      acc.w = a0 * hv[0].w + a1 * hv[1].w + a2 * hv[2].w + a3 * hv[3].w;
      if (t > 0) {
        float4 hp = load_bf4(h + (size_t)(j * 8192 + bt - 1) * 1024 + c4);
        acc.x += a4 * hp.x; acc.y += a4 * hp.y; acc.z += a4 * hp.z; acc.w += a4 * hp.w;
      }
      ushort4 o;
      o.x = f2bf(acc.x + bv.x); o.y = f2bf(acc.y + bv.y);
      o.z = f2bf(acc.z + bv.z); o.w = f2bf(acc.w + bv.w);
      *(ushort4*)(ob + (size_t)(j * 8192 + bt) * 1024 + c4) = o;
    }
  } else {
    __shared__ float red[4][1024];
#pragma unroll
    for (int j = 0; j < 4; ++j) {
      const float* al = &alpha[j][head][0];
      const float a0 = al[0], a1 = al[1], a2 = al[2], a3 = al[3], a4 = al[4];
      float4 acc;
      acc.x = a0 * hv[0].x + a1 * hv[1].x + a2 * hv[2].x + a3 * hv[3].x;
      acc.y = a0 * hv[0].y + a1 * hv[1].y + a2 * hv[2].y + a3 * hv[3].y;
      acc.z = a0 * hv[0].z + a1 * hv[1].z + a2 * hv[2].z + a3 * hv[3].z;
      acc.w = a0 * hv[0].w + a1 * hv[1].w + a2 * hv[2].w + a3 * hv[3].w;
      if (t > 0) {
        float4 hp = load_bf4(h + (size_t)(j * 8192 + bt - 1) * 1024 + c4);
        acc.x += a4 * hp.x; acc.y += a4 * hp.y; acc.z += a4 * hp.z; acc.w += a4 * hp.w;
      }
      *(float4*)(&red[j][c4]) = acc;
    }
    __syncthreads();
    const float bb = bias[tid];
    float* of = (float*)out;
#pragma unroll
    for (int j = 0; j < 4; ++j) {
      float v = 0.25f * (red[j][tid] + red[j][tid + 256] + red[j][tid + 512] +
                         red[j][tid + 768]) + bb;
      of[(size_t)(j * 8192 + bt) * 256 + tid] = v;
    }
  }
}

// ---------------- audio-dst aggregation (1 node per block) ------------------
// even ta: srcs {self, left_eye(b,ta/2), right_eye(b,ta/2)}; odd ta: self only.
template <bool MEAN>
__global__ __launch_bounds__(256) void audio_agg_kernel(
    const u16* __restrict__ h, const float* __restrict__ asb,
    const float* __restrict__ adb, const float* __restrict__ bias,
    void* __restrict__ out) {
  const int idx = blockIdx.x;  // b*1024 + ta
  const int ta = idx & 1023;
  const int node = 32768 + idx;
  const int tid = threadIdx.x;
  const bool even = ((ta & 1) == 0);
  __shared__ float alpha[4][3];
  int le = 0, re = 0;
  if (even) {
    const int b = idx >> 10;
    const int t = ta >> 1;
    le = 8192 + b * 512 + t;
    re = 16384 + b * 512 + t;
    if (tid < 4) {
      const int hh = tid;
      const float ad = adb[node * 4 + hh];
      float e0 = lrelu(asb[node * 4 + hh] + ad);
      float e1 = lrelu(asb[le * 4 + hh] + ad);
      float e2 = lrelu(asb[re * 4 + hh] + ad);
      float m = fmaxf(e0, fmaxf(e1, e2));
      float x0 = __expf(e0 - m), x1 = __expf(e1 - m), x2 = __expf(e2 - m);
      float inv = 1.f / (x0 + x1 + x2 + 1e-16f);
      alpha[hh][0] = x0 * inv; alpha[hh][1] = x1 * inv; alpha[hh][2] = x2 * inv;
    }
    __syncthreads();
  }
  const int c4 = tid * 4;
  const int head = tid >> 6;
  float4 v = load_bf4(h + (size_t)node * 1024 + c4);
  if (even) {
    float4 v1 = load_bf4(h + (size_t)le * 1024 + c4);
    float4 v2 = load_bf4(h + (size_t)re * 1024 + c4);
    const float a0 = alpha[head][0], a1 = alpha[head][1], a2 = alpha[head][2];
    v.x = a0 * v.x + a1 * v1.x + a2 * v2.x;
    v.y = a0 * v.y + a1 * v1.y + a2 * v2.y;
    v.z = a0 * v.z + a1 * v1.z + a2 * v2.z;
    v.w = a0 * v.w + a1 * v1.w + a2 * v2.w;
  }
  if constexpr (!MEAN) {
    const float4 bv = *(const float4*)(bias + c4);
    ushort4 o;
    o.x = f2bf(v.x + bv.x); o.y = f2bf(v.y + bv.y);
    o.z = f2bf(v.z + bv.z); o.w = f2bf(v.w + bv.w);
    *(ushort4*)((u16*)out + (size_t)node * 1024 + c4) = o;
  } else {
    __shared__ float red[1024];
    *(float4*)(&red[c4]) = v;
    __syncthreads();
    float* of = (float*)out;
    of[(size_t)node * 256 + tid] =
        0.25f * (red[tid] + red[tid + 256] + red[tid + 512] + red[tid + 768]) + bias[tid];
  }
}

// ---------------- LayerNorm(256) + partial chunk pooling --------------------
__global__ __launch_bounds__(256) void ln_pool_kernel(
    const float* __restrict__ xf, const float* __restrict__ g,
    const float* __restrict__ bb, float* __restrict__ part) {
  const int chunk = blockIdx.x / 48;
  const int sub = blockIdx.x % 48;
  const int n0 = chunk * 3072 + sub * 64;
  const int c = threadIdx.x;
  const int wave = c >> 6, lane = c & 63;
  __shared__ float ls[8];
  const float gc = g[c], bc = bb[c];
  float accum = 0.f;
  for (int i = 0; i < 64; ++i) {
    const float v = xf[(size_t)(n0 + i) * 256 + c];
    float s = v, q = v * v;
#pragma unroll
    for (int off = 32; off; off >>= 1) {
      s += __shfl_down(s, off);
      q += __shfl_down(q, off);
    }
    if (lane == 0) { ls[wave] = s; ls[4 + wave] = q; }
    __syncthreads();
    const float st = ls[0] + ls[1] + ls[2] + ls[3];
    const float qt = ls[4] + ls[5] + ls[6] + ls[7];
    __syncthreads();
    const float mean = st * (1.f / 256.f);
    const float var = qt * (1.f / 256.f) - mean * mean;
    accum += (v - mean) * rsqrtf(var + 1e-5f) * gc + bc;
  }
  part[(size_t)blockIdx.x * 256 + c] = accum;
}

__global__ __launch_bounds__(256) void pool2_kernel(const float* __restrict__ part,
                                                    float* __restrict__ out) {
  const int chunk = blockIdx.x;
  const int c = threadIdx.x;
  float s = 0.f;
  for (int i = 0; i < 48; ++i) s += part[(size_t)(chunk * 48 + i) * 256 + c];
  out[chunk * 256 + c] = s * (1.f / 3072.f);
}

// ---------------------------------------------------------------------------
extern "C" void kernel_launch(void* const* d_in, const int* in_sizes, int n_in,
                              void* d_out, int out_size, void* d_ws, size_t ws_size,
                              hipStream_t stream) {
  const float* x_reg[4] = {(const float*)d_in[0], (const float*)d_in[1],
                           (const float*)d_in[2], (const float*)d_in[3]};
  const float* audio = (const float*)d_in[4];
  const float* w_reg[4] = {(const float*)d_in[5], (const float*)d_in[7],
                           (const float*)d_in[9], (const float*)d_in[11]};
  const float* b_reg[4] = {(const float*)d_in[6], (const float*)d_in[8],
                           (const float*)d_in[10], (const float*)d_in[12]};
  const float* w_aud = (const float*)d_in[13];
  const float* b_aud = (const float*)d_in[14];
  const float* Wl[3] = {(const float*)d_in[15], (const float*)d_in[19],
                        (const float*)d_in[23]};
  const float* as_in[3] = {(const float*)d_in[16], (const float*)d_in[20],
                           (const float*)d_in[24]};
  const float* ad_in[3] = {(const float*)d_in[17], (const float*)d_in[21],
                           (const float*)d_in[25]};
  const float* bias_l[3] = {(const float*)d_in[18], (const float*)d_in[22],
                            (const float*)d_in[26]};
  const float* ln_g = (const float*)d_in[27];
  const float* ln_b = (const float*)d_in[28];

  // workspace layout (~200 MiB)
  char* ws = (char*)d_ws;
  u16* h_bf = (u16*)ws;                       // [N,1024] bf16; aliased input staging
  u16* in_bf = h_bf;                          // [N,512] bf16 (dead before L0 writes h)
  u16* xb = (u16*)(ws + 100663296);           // [N,1024] bf16 x buffer (in-place ping)
  float* xf = (float*)xb;                     // layer-2 output [N,256] fp32
  float* asb = (float*)(ws + 201326592);      // [N,4]
  float* adb = (float*)(ws + 202113024);      // [N,4]
  u16* wt = (u16*)(ws + 202899456);           // transposed bf16 weights
  float* part = (float*)(ws + 208928768);     // 768*256 pooling partials

  u16* wtp[5];
  for (int r = 0; r < 5; ++r) wtp[r] = wt + (size_t)r * 131072;  // [256][512]
  u16* wt0 = wt + 655360;   // [1024][256]
  u16* wt1 = wt + 917504;   // [1024][1024]
  u16* wt2 = wt + 1966080;  // [1024][1024]

  // 1) inputs -> bf16 (contiguous [N,512], node-ordered), single dispatch
  CvtArgs ca;
  for (int r = 0; r < 4; ++r) ca.p[r] = x_reg[r];
  ca.p[4] = audio;
  cvt_all_kernel<<<24576, 256, 0, stream>>>(ca, in_bf);

  // 2) weights -> transposed bf16
  dim3 tb(32, 8);
  for (int r = 0; r < 4; ++r)
    transpose_cvt_kernel<<<dim3(16, 8), tb, 0, stream>>>(w_reg[r], wtp[r], 512, 256);
  transpose_cvt_kernel<<<dim3(16, 8), tb, 0, stream>>>(w_aud, wtp[4], 512, 256);
  transpose_cvt_kernel<<<dim3(8, 32), tb, 0, stream>>>(Wl[0], wt0, 256, 1024);
  transpose_cvt_kernel<<<dim3(32, 32), tb, 0, stream>>>(Wl[1], wt1, 1024, 1024);
  transpose_cvt_kernel<<<dim3(32, 32), tb, 0, stream>>>(Wl[2], wt2, 1024, 1024);

  // 3) input projections -> x0 bf16 [N,256], single fused dispatch
  ProjArgs pa;
  for (int r = 0; r < 5; ++r) { pa.w[r] = wtp[r]; }
  for (int r = 0; r < 4; ++r) { pa.b[r] = b_reg[r]; }
  pa.b[4] = b_aud;
  proj_gemm_kernel<<<dim3(2, 384), 256, 0, stream>>>(pa, in_bf, xb);

  // 4) three GAT layers
  const u16* wl[3] = {wt0, wt1, wt2};
  const int Kl[3] = {256, 1024, 1024};
  for (int l = 0; l < 3; ++l) {
    gemm_kernel<<<dim3(8, 384), 256, 0, stream>>>(xb, wl[l], h_bf, nullptr, Kl[l], 1024);
    alpha_kernel<<<49152, 256, 0, stream>>>(h_bf, as_in[l], ad_in[l], asb, adb);
    if (l < 2) {
      region_agg_kernel<false><<<8192, 256, 0, stream>>>(h_bf, asb, adb, bias_l[l], xb);
      audio_agg_kernel<false><<<16384, 256, 0, stream>>>(h_bf, asb, adb, bias_l[l], xb);
    } else {
      region_agg_kernel<true><<<8192, 256, 0, stream>>>(h_bf, asb, adb, bias_l[l], xf);
      audio_agg_kernel<true><<<16384, 256, 0, stream>>>(h_bf, asb, adb, bias_l[l], xf);
    }
  }

  // 5) LayerNorm + chunk pooling -> out [16,256]
  ln_pool_kernel<<<768, 256, 0, stream>>>(xf, ln_g, ln_b, part);
  pool2_kernel<<<16, 256, 0, stream>>>(part, (float*)d_out);
}